// Round 1
// baseline (257.050 us; speedup 1.0000x reference)
//
#include <hip/hip_runtime.h>
#include <stdint.h>
#include <math.h>

using short8 = __attribute__((ext_vector_type(8))) short;
using f32x4  = __attribute__((ext_vector_type(4))) float;

#define DEV __device__ __forceinline__

DEV unsigned short f2bf(float f) {
    union { float f; unsigned u; } c; c.f = f;
    unsigned u = c.u;
    unsigned r = (u + 0x7FFFu + ((u >> 16) & 1u)) >> 16;
    return (unsigned short)r;
}

DEV void gld16(const unsigned short* g, unsigned short* l) {
    __builtin_amdgcn_global_load_lds(
        (const __attribute__((address_space(1))) void*)g,
        (__attribute__((address_space(3))) void*)l, 16, 0, 0);
}

// ---------------- transpose fp32 [K][N] -> bf16 [N][K] ----------------
__global__ __launch_bounds__(256) void k_transpose_bf16(
    const float* __restrict__ W, unsigned short* __restrict__ Wt, int K, int N)
{
    __shared__ float tile[32][33];
    int tx = threadIdx.x, ty = threadIdx.y;
    int n0 = blockIdx.x * 32, k0 = blockIdx.y * 32;
#pragma unroll
    for (int i = 0; i < 4; i++) {
        int k = k0 + ty + i * 8;
        tile[ty + i * 8][tx] = W[(size_t)k * N + n0 + tx];
    }
    __syncthreads();
#pragma unroll
    for (int i = 0; i < 4; i++) {
        int n = n0 + ty + i * 8;
        Wt[(size_t)n * K + k0 + tx] = f2bf(tile[tx][ty + i * 8]);
    }
}

// ---------------- layernorm fp32 row(768) -> bf16 ----------------
__global__ __launch_bounds__(256) void k_layernorm(
    const float* __restrict__ x, const float* __restrict__ g,
    const float* __restrict__ b, unsigned short* __restrict__ out)
{
    int row = blockIdx.x;
    int tid = threadIdx.x;
    const float* xr = x + (size_t)row * 768;
    float v0 = xr[tid], v1 = xr[tid + 256], v2 = xr[tid + 512];
    float s1 = v0 + v1 + v2;
    float s2 = v0 * v0 + v1 * v1 + v2 * v2;
#pragma unroll
    for (int off = 32; off >= 1; off >>= 1) {
        s1 += __shfl_down(s1, off);
        s2 += __shfl_down(s2, off);
    }
    __shared__ float red[8];
    int wid = tid >> 6, lane = tid & 63;
    if (lane == 0) { red[wid] = s1; red[4 + wid] = s2; }
    __syncthreads();
    s1 = red[0] + red[1] + red[2] + red[3];
    s2 = red[4] + red[5] + red[6] + red[7];
    float mu = s1 * (1.0f / 768.0f);
    float var = s2 * (1.0f / 768.0f) - mu * mu;
    float rs = rsqrtf(var + 1e-5f);
    unsigned short* orow = out + (size_t)row * 768;
    orow[tid]       = f2bf((v0 - mu) * rs * g[tid]       + b[tid]);
    orow[tid + 256] = f2bf((v1 - mu) * rs * g[tid + 256] + b[tid + 256]);
    orow[tid + 512] = f2bf((v2 - mu) * rs * g[tid + 512] + b[tid + 512]);
}

// ---------------- GEMM: C[M,N] = A[M,K] * Bt[N,K]^T, bf16 in, fused epilogue ----------------
// EPI 0: qkv scatter  1: proj(+bias+resid->f32)  2: fc1(+bias+gelu->bf16)  3: fc2(+bias+resid->f32)
template<int EPI>
__global__ __launch_bounds__(256) void k_gemm(
    const unsigned short* __restrict__ A, const unsigned short* __restrict__ Bt,
    int M, int N, int K,
    const float* __restrict__ bias, const float* __restrict__ resid,
    float* __restrict__ outF, unsigned short* __restrict__ outH,
    unsigned short* __restrict__ qb, unsigned short* __restrict__ kb,
    unsigned short* __restrict__ vtb)
{
    __shared__ __align__(16) unsigned short As[128 * 32];
    __shared__ __align__(16) unsigned short Bs[128 * 32];
    int tid = threadIdx.x;
    int lane = tid & 63, wid = tid >> 6;
    int m0 = blockIdx.x * 128, n0 = blockIdx.y * 128;
    int wr = (wid >> 1) * 64, wc = (wid & 1) * 64;
    int fr = lane & 15, fg = lane >> 4;

    f32x4 zero4 = {0.f, 0.f, 0.f, 0.f};
    f32x4 acc[4][4];
#pragma unroll
    for (int mi = 0; mi < 4; mi++)
#pragma unroll
        for (int nj = 0; nj < 4; nj++) acc[mi][nj] = zero4;

    // staging: per 64-row issue set, lane covers (row = srow, 16B chunk = schk swizzled)
    int srow = wid * 16 + (lane >> 2);
    int schk = (lane & 3) ^ ((lane >> 2) & 3);
    const unsigned short* agp0 = A  + (size_t)(m0 + srow) * K      + schk * 8;
    const unsigned short* agp1 = A  + (size_t)(m0 + srow + 64) * K + schk * 8;
    const unsigned short* bgp0 = Bt + (size_t)(n0 + srow) * K      + schk * 8;
    const unsigned short* bgp1 = Bt + (size_t)(n0 + srow + 64) * K + schk * 8;
    unsigned short* alds0 = As + wid * 512;
    unsigned short* alds1 = As + wid * 512 + 2048;
    unsigned short* blds0 = Bs + wid * 512;
    unsigned short* blds1 = Bs + wid * 512 + 2048;

    // frag read: row = wr/wc + t*16 + fr, wanted chunk fg, stored at pos fg^(row&3)
    int posA = fg ^ (fr & 3);
    int aoff = (wr + fr) * 32 + posA * 8;
    int boff = (wc + fr) * 32 + posA * 8;

    for (int kt = 0; kt < K; kt += 32) {
        gld16(agp0 + kt, alds0);
        gld16(agp1 + kt, alds1);
        gld16(bgp0 + kt, blds0);
        gld16(bgp1 + kt, blds1);
        __syncthreads();
        short8 af[4], bfv[4];
#pragma unroll
        for (int mi = 0; mi < 4; mi++) af[mi]  = *(const short8*)(As + aoff + mi * 512);
#pragma unroll
        for (int nj = 0; nj < 4; nj++) bfv[nj] = *(const short8*)(Bs + boff + nj * 512);
#pragma unroll
        for (int mi = 0; mi < 4; mi++)
#pragma unroll
            for (int nj = 0; nj < 4; nj++)
                acc[mi][nj] = __builtin_amdgcn_mfma_f32_16x16x32_bf16(
                    af[mi], bfv[nj], acc[mi][nj], 0, 0, 0);
        __syncthreads();
    }

#pragma unroll
    for (int mi = 0; mi < 4; mi++) {
#pragma unroll
        for (int nj = 0; nj < 4; nj++) {
#pragma unroll
            for (int i = 0; i < 4; i++) {
                int grow = m0 + wr + mi * 16 + fg * 4 + i;
                int gcol = n0 + wc + nj * 16 + fr;
                float v = acc[mi][nj][i];
                if (EPI == 0) {
                    int part = gcol / 768;
                    int wi = gcol - part * 768;
                    int head = wi >> 6, d = wi & 63;
                    int bb = grow >> 10, n = grow & 1023;
                    size_t base = ((size_t)(bb * 12 + head)) << 16;
                    unsigned short bv = f2bf(v);
                    if (part == 0)      qb[base + (size_t)n * 64 + d] = bv;
                    else if (part == 1) kb[base + (size_t)n * 64 + d] = bv;
                    else                vtb[base + (size_t)d * 1024 + n] = bv;
                } else if (EPI == 2) {
                    float t = v + bias[gcol];
                    outH[(size_t)grow * 768 + gcol] =
                        f2bf(0.5f * t * (1.0f + erff(t * 0.70710678118f)));
                } else { // 1 and 3: +bias+residual -> f32
                    size_t idx = (size_t)grow * 768 + gcol;
                    outF[idx] = v + bias[gcol] + resid[idx];
                }
            }
        }
    }
}

// ---------------- flash attention ----------------
// Q,K: [bh][n][64] bf16;  Vt: [bh][64][n] bf16;  O: [b*1024+n][768] bf16 (col = h*64+d)
__global__ __launch_bounds__(256) void k_attn(
    const unsigned short* __restrict__ Q, const unsigned short* __restrict__ Kk,
    const unsigned short* __restrict__ Vt, const int* __restrict__ mask,
    unsigned short* __restrict__ O)
{
    __shared__ __align__(16) unsigned short Ks[64 * 64];
    __shared__ __align__(16) unsigned short Vs[64 * 64];
    __shared__ __align__(16) unsigned short Ps[4][16 * 72];
    __shared__ int msk[1024];

    int tid = threadIdx.x, lane = tid & 63, wid = tid >> 6;
    int qt = blockIdx.x;   // 16 q-tiles of 64
    int bh = blockIdx.y;   // b*12+h
    int b = bh / 12;
    int hh = bh - b * 12;
    int fr = lane & 15, fg = lane >> 4;

    const unsigned short* qg = Q  + ((size_t)bh << 16);
    const unsigned short* kg = Kk + ((size_t)bh << 16);
    const unsigned short* vg = Vt + ((size_t)bh << 16);

    for (int i = tid; i < 1024; i += 256) msk[i] = mask[b * 1024 + i];

    short8 qf[2];
    {
        const unsigned short* qp = qg + (size_t)(qt * 64 + wid * 16 + fr) * 64 + fg * 8;
        qf[0] = *(const short8*)(qp);
        qf[1] = *(const short8*)(qp + 32);
    }

    f32x4 zero4 = {0.f, 0.f, 0.f, 0.f};
    f32x4 oacc[4];
    float m_run[4], l_run[4];
#pragma unroll
    for (int i = 0; i < 4; i++) { m_run[i] = -INFINITY; l_run[i] = 0.f; }
#pragma unroll
    for (int df = 0; df < 4; df++) oacc[df] = zero4;

    __syncthreads();  // msk ready
    int mq[4];
#pragma unroll
    for (int i = 0; i < 4; i++) mq[i] = msk[qt * 64 + wid * 16 + fg * 4 + i];

    // staging geometry: per 32-row set, lane -> row = wid*8 + (lane>>3), chunk pos = lane&7
    int srow = wid * 8 + (lane >> 3);
    int schk = (lane & 7) ^ ((lane >> 3) & 7);
    const unsigned short* kgp = kg + (size_t)srow * 64 + schk * 8;
    const unsigned short* vgp = vg + (size_t)srow * 1024 + schk * 8;
    unsigned short* kl0 = Ks + wid * 512;
    unsigned short* kl1 = Ks + wid * 512 + 2048;
    unsigned short* vl0 = Vs + wid * 512;
    unsigned short* vl1 = Vs + wid * 512 + 2048;

    const float scale = 0.125f;

    for (int kc = 0; kc < 16; ++kc) {
        gld16(kgp + (size_t)(kc * 64) * 64, kl0);
        gld16(kgp + (size_t)(kc * 64 + 32) * 64, kl1);
        gld16(vgp + kc * 64, vl0);
        gld16(vgp + 32 * 1024 + kc * 64, vl1);
        __syncthreads();

        // S = Q K^T (wave: 16 q-rows x 64 keys)
        f32x4 s[4];
#pragma unroll
        for (int nf = 0; nf < 4; ++nf) {
            int row = nf * 16 + fr;
            int pos0 = fg ^ (fr & 7);
            int pos1 = (fg + 4) ^ (fr & 7);
            short8 b0 = *(const short8*)(Ks + row * 64 + pos0 * 8);
            short8 b1 = *(const short8*)(Ks + row * 64 + pos1 * 8);
            f32x4 a = zero4;
            a = __builtin_amdgcn_mfma_f32_16x16x32_bf16(qf[0], b0, a, 0, 0, 0);
            a = __builtin_amdgcn_mfma_f32_16x16x32_bf16(qf[1], b1, a, 0, 0, 0);
            s[nf] = a;
        }

        float sv[4][4];
#pragma unroll
        for (int nf = 0; nf < 4; nf++) {
            int mk = msk[kc * 64 + nf * 16 + fr];
#pragma unroll
            for (int i = 0; i < 4; i++)
                sv[nf][i] = (mk && mq[i]) ? s[nf][i] * scale : -1e9f;
        }

        float mnew[4], alpha[4];
#pragma unroll
        for (int i = 0; i < 4; i++) {
            float cm = fmaxf(fmaxf(sv[0][i], sv[1][i]), fmaxf(sv[2][i], sv[3][i]));
            cm = fmaxf(cm, __shfl_xor(cm, 1));
            cm = fmaxf(cm, __shfl_xor(cm, 2));
            cm = fmaxf(cm, __shfl_xor(cm, 4));
            cm = fmaxf(cm, __shfl_xor(cm, 8));
            mnew[i] = fmaxf(m_run[i], cm);
            alpha[i] = __expf(m_run[i] - mnew[i]);
            m_run[i] = mnew[i];
        }

        float rsum[4] = {0.f, 0.f, 0.f, 0.f};
#pragma unroll
        for (int nf = 0; nf < 4; nf++) {
#pragma unroll
            for (int i = 0; i < 4; i++) {
                float p = __expf(sv[nf][i] - mnew[i]);
                rsum[i] += p;
                Ps[wid][(fg * 4 + i) * 72 + nf * 16 + fr] = f2bf(p);
            }
        }
#pragma unroll
        for (int i = 0; i < 4; i++) {
            float r = rsum[i];
            r += __shfl_xor(r, 1);
            r += __shfl_xor(r, 2);
            r += __shfl_xor(r, 4);
            r += __shfl_xor(r, 8);
            l_run[i] = l_run[i] * alpha[i] + r;
        }
#pragma unroll
        for (int df = 0; df < 4; df++)
#pragma unroll
            for (int i = 0; i < 4; i++) oacc[df][i] *= alpha[i];

        // O += P V
#pragma unroll
        for (int kf2 = 0; kf2 < 2; ++kf2) {
            short8 pa = *(const short8*)(&Ps[wid][fr * 72 + kf2 * 32 + fg * 8]);
#pragma unroll
            for (int df = 0; df < 4; df++) {
                int rv = df * 16 + fr;
                int pos = (kf2 * 4 + fg) ^ (fr & 7);
                short8 vb = *(const short8*)(Vs + rv * 64 + pos * 8);
                oacc[df] = __builtin_amdgcn_mfma_f32_16x16x32_bf16(pa, vb, oacc[df], 0, 0, 0);
            }
        }
        __syncthreads();
    }

#pragma unroll
    for (int i = 0; i < 4; i++) {
        float inv = 1.0f / l_run[i];
        size_t rowbase = ((size_t)(b * 1024 + qt * 64 + wid * 16 + fg * 4 + i)) * 768
                         + hh * 64 + fr;
#pragma unroll
        for (int df = 0; df < 4; df++)
            O[rowbase + df * 16] = f2bf(oacc[df][i] * inv);
    }
}

// ---------------- launch ----------------
extern "C" void kernel_launch(void* const* d_in, const int* in_sizes, int n_in,
                              void* d_out, int out_size, void* d_ws, size_t ws_size,
                              hipStream_t stream)
{
    const float* x      = (const float*)d_in[0];
    const int*   mask   = (const int*)d_in[1];
    const float* g1     = (const float*)d_in[2];
    const float* b1     = (const float*)d_in[3];
    const float* w_qkv  = (const float*)d_in[4];
    const float* w_proj = (const float*)d_in[5];
    const float* b_proj = (const float*)d_in[6];
    const float* g2     = (const float*)d_in[7];
    const float* b2     = (const float*)d_in[8];
    const float* w_fc1  = (const float*)d_in[9];
    const float* b_fc1  = (const float*)d_in[10];
    const float* w_fc2  = (const float*)d_in[11];
    const float* b_fc2  = (const float*)d_in[12];
    float* out = (float*)d_out;

    char* ws = (char*)d_ws;
    unsigned short* wqkv_t  = (unsigned short*)(ws + 0);
    unsigned short* wproj_t = (unsigned short*)(ws + 3538944);
    unsigned short* wfc1_t  = (unsigned short*)(ws + 4718592);
    unsigned short* wfc2_t  = (unsigned short*)(ws + 5898240);
    unsigned short* bufA    = (unsigned short*)(ws + 7077888);   // h / h2
    unsigned short* bufB    = (unsigned short*)(ws + 19660800);  // o / gelu-out
    unsigned short* qb      = (unsigned short*)(ws + 32243712);
    unsigned short* kb      = (unsigned short*)(ws + 44826624);
    unsigned short* vtb     = (unsigned short*)(ws + 57409536);
    float*          x1      = (float*)(ws + 69992448);
    // total: 95,158,272 bytes

    dim3 tb(32, 8);
    k_transpose_bf16<<<dim3(2304 / 32, 768 / 32), tb, 0, stream>>>(w_qkv, wqkv_t, 768, 2304);
    k_transpose_bf16<<<dim3(768 / 32, 768 / 32), tb, 0, stream>>>(w_proj, wproj_t, 768, 768);
    k_transpose_bf16<<<dim3(768 / 32, 768 / 32), tb, 0, stream>>>(w_fc1, wfc1_t, 768, 768);
    k_transpose_bf16<<<dim3(768 / 32, 768 / 32), tb, 0, stream>>>(w_fc2, wfc2_t, 768, 768);

    k_layernorm<<<8192, 256, 0, stream>>>(x, g1, b1, bufA);

    k_gemm<0><<<dim3(64, 18), 256, 0, stream>>>(bufA, wqkv_t, 8192, 2304, 768,
        nullptr, nullptr, nullptr, nullptr, qb, kb, vtb);

    k_attn<<<dim3(16, 96), 256, 0, stream>>>(qb, kb, vtb, mask, bufB);

    k_gemm<1><<<dim3(64, 6), 256, 0, stream>>>(bufB, wproj_t, 8192, 768, 768,
        b_proj, x, x1, nullptr, nullptr, nullptr, nullptr);

    k_layernorm<<<8192, 256, 0, stream>>>(x1, g2, b2, bufA);

    k_gemm<2><<<dim3(64, 6), 256, 0, stream>>>(bufA, wfc1_t, 8192, 768, 768,
        b_fc1, nullptr, nullptr, bufB, nullptr, nullptr, nullptr);

    k_gemm<3><<<dim3(64, 6), 256, 0, stream>>>(bufB, wfc2_t, 8192, 768, 768,
        b_fc2, x1, out, nullptr, nullptr, nullptr, nullptr);
}